// Round 1
// baseline (328.032 us; speedup 1.0000x reference)
//
#include <hip/hip_runtime.h>
#include <math.h>

#define NN 1024
#define FD 64
#define CH 32          // K*H
#define M1D 9
#define M2D 505
#define QH 253         // q in [0,252] stored
#define THALF 2273     // half-grid points
#define KPAD 4608
#define KSPLIT 16
#define KCHUNK 288     // 4608/16, = 9*32

// ws layout (floats)
#define OFF_TW    0                       // 1010 (pad 1024)
#define OFF_WP    1024                    // 18 (pad 32)
#define OFF_SUMX  1056                    // 128
#define OFF_G1    1184                    // 9*253*64*2 = 291456
#define OFF_GMAT  292640                  // 4608*64 = 294912
#define OFF_XL    587552                  // 65536
#define OFF_XR    653088                  // 65536
#define OFF_AGG   718624                  // 2048*512 = 1048576
#define OFF_Y     1767200                 // 2048*4608 = 9437184
// total = 11,204,384 floats = 44.8 MB

__global__ __launch_bounds__(512) void prep_kernel(float* __restrict__ tw,
                                                   float* __restrict__ wp,
                                                   float* __restrict__ sumx) {
    int t = threadIdx.x;
    if (t < M2D) {
        double a = -2.0 * M_PI * (double)t / (double)M2D;
        tw[2*t] = (float)cos(a); tw[2*t+1] = (float)sin(a);
    }
    if (t < M1D) {
        double a = -2.0 * M_PI * (double)t / (double)M1D;
        wp[2*t] = (float)cos(a); wp[2*t+1] = (float)sin(a);
    }
    if (t < 128) sumx[t] = 0.f;
}

// 32 blocks x 64 threads: partial column sums of x, atomically accumulated
__global__ __launch_bounds__(64) void sumx_kernel(const float* __restrict__ x,
                                                  float* __restrict__ sumx) {
    int b = blockIdx.x >> 4, chunk = blockIdx.x & 15;
    int f = threadIdx.x;
    const float* xb = x + (size_t)b * NN * FD;
    float acc = 0.f;
    int j0 = chunk * 64;
    #pragma unroll 4
    for (int j = j0; j < j0 + 64; j++) acc += xb[j*FD + f];
    atomicAdd(&sumx[b*FD + f], acc);
}

// 2048 blocks x 64 threads: xl = x@Wl+bl, xr = x@Wr+br
__global__ __launch_bounds__(64) void proj_kernel(const float* __restrict__ x,
                                                  const float* __restrict__ Wl, const float* __restrict__ bl,
                                                  const float* __restrict__ Wr, const float* __restrict__ br,
                                                  float* __restrict__ xl, float* __restrict__ xr) {
    int node = blockIdx.x, tid = threadIdx.x;
    __shared__ float xrow[FD];
    xrow[tid] = x[(size_t)node*FD + tid];
    __syncthreads();
    int c = tid & 31;
    const float* W = (tid < 32) ? Wl : Wr;
    float acc = (tid < 32) ? bl[c] : br[c];
    #pragma unroll
    for (int f = 0; f < FD; f++) acc += xrow[f] * W[f*CH + c];
    float* dst = (tid < 32) ? xl : xr;
    dst[(size_t)node*CH + c] = acc;
}

// G1[m1,q,f] = sum_m2 Wm[m1*505+m2, f] * cis(+2*pi*q*m2/505), q in [0,253)
__global__ __launch_bounds__(64) void g1_kernel(const float* __restrict__ Wm,
                                                const float* __restrict__ tw,
                                                float* __restrict__ G1) {
    int blk = blockIdx.x;          // 9*253
    int m1 = blk / QH, q = blk % QH;
    int f = threadIdx.x;
    __shared__ float twL[M2D*2];
    for (int i = threadIdx.x; i < M2D*2; i += 64) twL[i] = tw[i];
    __syncthreads();
    const float* Wrow = Wm + (size_t)m1 * M2D * FD;
    float ar = 0.f, ai = 0.f;
    int t = 0;
    for (int m2 = 0; m2 < M2D; m2++) {
        float w = Wrow[(size_t)m2*FD + f];
        ar += w * twL[2*t];          // cos(+a) = cos(-a)
        ai -= w * twL[2*t+1];        // sin(+a) = -sin(-a)
        t += q; if (t >= M2D) t -= M2D;
    }
    size_t o = ((size_t)(m1*QH + q)*FD + f)*2;
    G1[o] = ar; G1[o+1] = ai;
}

// Gmat[2t..2t+1][f] from G1: fold 9-point DFT over m1, Hermitian weight c, 1/4545
__global__ __launch_bounds__(64) void gmat_kernel(const float* __restrict__ G1,
                                                  const float* __restrict__ wp,
                                                  float* __restrict__ Gmat) {
    int t = blockIdx.x;            // [0, 2304)
    int f = threadIdx.x;
    if (t >= THALF) {
        Gmat[(size_t)(2*t)*FD + f] = 0.f;
        Gmat[(size_t)(2*t+1)*FD + f] = 0.f;
        return;
    }
    int p, q;
    if (t < QH) { p = 0; q = t; }
    else { int u = t - QH; p = 1 + u / M2D; q = u % M2D; }
    float gr = 0.f, gi = 0.f;
    #pragma unroll
    for (int m1 = 0; m1 < M1D; m1++) {
        float ar, ai;
        if (q < QH) { size_t o = ((size_t)(m1*QH + q)*FD + f)*2; ar = G1[o]; ai = G1[o+1]; }
        else        { size_t o = ((size_t)(m1*QH + (M2D - q))*FD + f)*2; ar = G1[o]; ai = -G1[o+1]; }
        int pm = (p * m1) % M1D;
        float cr = wp[2*pm], ci = -wp[2*pm+1];   // cis(+2 pi p m1 / 9)
        gr += ar*cr - ai*ci;
        gi += ar*ci + ai*cr;
    }
    float cfac = (t == 0) ? 1.0f : 2.0f;
    float scale = cfac / 4545.0f;
    Gmat[(size_t)(2*t)*FD + f]   =  gr * scale;
    Gmat[(size_t)(2*t+1)*FD + f] = -gi * scale;
}

// one block (256 thr) per node: softmax Z over all j, sparse clamped gather
__global__ __launch_bounds__(256) void attn_agg_kernel(const float* __restrict__ x,
                                                       const float* __restrict__ adj,
                                                       const float* __restrict__ xl,
                                                       const float* __restrict__ xr,
                                                       const float* __restrict__ sumx,
                                                       float* __restrict__ agg) {
    int node = blockIdx.x;
    int b = node >> 10;
    int tid = threadIdx.x;
    __shared__ float xr_s[CH], Zinv[CH], Ssum[CH];
    __shared__ float red[8][CH];
    __shared__ int act_list[NN];
    __shared__ int act_n;
    __shared__ float qv[8][CH];

    if (tid < CH) xr_s[tid] = xr[(size_t)node*CH + tid];
    if (tid == 0) act_n = 0;
    __syncthreads();

    int c = tid & 31, jl = tid >> 5;
    const float* xlb = xl + ((size_t)b << 10) * CH;
    float zacc = 0.f;
    #pragma unroll 4
    for (int j = jl; j < NN; j += 8) {
        float s = xlb[j*CH + c] + xr_s[c];
        s = s > 0.f ? s : 0.01f * s;
        zacc += __expf(s);
    }
    red[jl][c] = zacc;
    __syncthreads();
    if (tid < CH) {
        float z = 0.f;
        #pragma unroll
        for (int r = 0; r < 8; r++) z += red[r][tid];
        Zinv[tid] = 1.0f / z;
    }
    const float* adjrow = adj + (size_t)node * NN;
    __syncthreads();
    for (int j = tid; j < NN; j += 256) {
        if (adjrow[j] != 0.f) { int p = atomicAdd(&act_n, 1); act_list[p] = j; }
    }
    __syncthreads();
    int nact = act_n;

    float acc0 = 0.f, acc1 = 0.f, sacc = 0.f;
    int f = tid & 63, n0 = tid >> 6;
    int g = f >> 4;
    int c0 = n0*4 + g, c1 = (n0+4)*4 + g;
    const float* xb = x + ((size_t)b << 10) * FD;

    for (int base = 0; base < nact; base += 8) {
        int cnt = min(8, nact - base);
        if (jl < cnt) {
            int j = act_list[base + jl];
            float s = xlb[j*CH + c] + xr_s[c];
            s = s > 0.f ? s : 0.01f * s;
            float p = __expf(s) * Zinv[c];
            float qq = fmaxf(p, 1e-6f) - 1e-6f;
            qv[jl][c] = qq;
            sacc += qq;
        }
        __syncthreads();
        for (int jb = 0; jb < cnt; jb++) {
            int j = act_list[base + jb];
            float xv = xb[j*FD + f];
            acc0 += qv[jb][c0] * xv;
            acc1 += qv[jb][c1] * xv;
        }
        __syncthreads();
    }
    red[jl][c] = sacc;
    __syncthreads();
    if (tid < CH) {
        float s = 0.f;
        #pragma unroll
        for (int r = 0; r < 8; r++) s += red[r][tid];
        Ssum[tid] = s + (float)NN * 1e-6f;
    }
    __syncthreads();
    float sx = sumx[b*FD + f] * 1e-6f;
    agg[(size_t)node*512 + n0*FD + f]       = (acc0 + sx) / Ssum[c0];
    agg[(size_t)node*512 + (n0+4)*FD + f]   = (acc1 + sx) / Ssum[c1];
}

// one block (256 thr) per node: A_n(q) DFT, then Y half-grid via complex product
__global__ __launch_bounds__(256) void fft_y_kernel(const float* __restrict__ agg,
                                                    const float* __restrict__ tw_g,
                                                    const float* __restrict__ wp_g,
                                                    float* __restrict__ Y) {
    int node = blockIdx.x;
    int tid = threadIdx.x;
    __shared__ float aggL[8][FD];
    __shared__ float twL[M2D*2];
    __shared__ float wpL[M1D*2];
    __shared__ float A[8][QH][2];

    for (int idx = tid; idx < 512; idx += 256) aggL[idx>>6][idx&63] = agg[(size_t)node*512 + idx];
    for (int idx = tid; idx < M2D*2; idx += 256) twL[idx] = tw_g[idx];
    if (tid < M1D*2) wpL[tid] = wp_g[tid];
    __syncthreads();

    for (int idx = tid; idx < 8*QH; idx += 256) {
        int n = idx / QH, q = idx % QH;
        float ar = 0.f, ai = 0.f;
        const float* ag = aggL[n];
        int t = 0;
        #pragma unroll 8
        for (int m = 0; m < FD; m++) {
            float v = ag[m];
            ar += v * twL[2*t];
            ai += v * twL[2*t+1];
            t += q; if (t >= M2D) t -= M2D;
        }
        A[n][q][0] = ar; A[n][q][1] = ai;
    }
    __syncthreads();

    float* Yrow = Y + (size_t)node * KPAD;
    for (int t = tid; t < KPAD/2; t += 256) {
        if (t >= THALF) { Yrow[2*t] = 0.f; Yrow[2*t+1] = 0.f; continue; }
        int p, q;
        if (t < QH) { p = 0; q = t; }
        else { int u = t - QH; p = 1 + u / M2D; q = u % M2D; }
        float cp = wpL[2*p], sp = wpL[2*p+1];      // e^{-2 pi i p / 9}
        int qq; float csign;
        if (q < QH) { qq = q; csign = 1.f; } else { qq = M2D - q; csign = -1.f; }
        float Pr = 1.f, Pi = 0.f, rp = 1.f;
        #pragma unroll
        for (int n = 0; n < 8; n++) {
            float Ar = A[n][qq][0], Ai = csign * A[n][qq][1];
            float Xr = cp - Ar, Xi = sp - Ai;
            float m2 = Xr*Xr + Xi*Xi;
            rp *= (sqrtf(m2) + 1e-6f);
            float nPr = Pr*Xr - Pi*Xi;
            Pi = Pr*Xi + Pi*Xr; Pr = nPr;
        }
        float pAbs = sqrtf(Pr*Pr + Pi*Pi);
        float rp8 = sqrtf(sqrtf(sqrtf(rp)));
        float s = rp8 / fmaxf(pAbs, 1e-20f);
        Yrow[2*t]   = s * Pr;
        Yrow[2*t+1] = s * Pi;
    }
}

__global__ __launch_bounds__(256) void out_init_kernel(float* __restrict__ out) {
    int idx = blockIdx.x * 256 + threadIdx.x;
    if (idx < 2048*FD) out[idx] = 0.f;
}

// out += Y @ Gmat ; grid (32 Mtiles, 16 Ksplit), 256 threads, 64x64 tile
__global__ __launch_bounds__(256) void gemm_kernel(const float* __restrict__ Y,
                                                   const float* __restrict__ Gmat,
                                                   float* __restrict__ out) {
    int mtile = blockIdx.x, kc = blockIdx.y;
    int tid = threadIdx.x;
    __shared__ float Yt[64][33];
    __shared__ float Gt[32][64];
    int m0 = mtile * 64;
    int k0 = kc * KCHUNK;
    float acc[4][4] = {{0.f}};
    int tm = (tid >> 4) * 4;
    int tf = (tid & 15) * 4;
    for (int ks = 0; ks < KCHUNK; ks += 32) {
        for (int l = tid; l < 2048; l += 256) {
            int r = l >> 5, cc = l & 31;
            Yt[r][cc] = Y[(size_t)(m0 + r)*KPAD + k0 + ks + cc];
        }
        for (int l = tid; l < 2048; l += 256) {
            int r = l >> 6, cc = l & 63;
            Gt[r][cc] = Gmat[(size_t)(k0 + ks + r)*FD + cc];
        }
        __syncthreads();
        #pragma unroll 8
        for (int k = 0; k < 32; k++) {
            float a0 = Yt[tm][k], a1 = Yt[tm+1][k], a2 = Yt[tm+2][k], a3 = Yt[tm+3][k];
            float b0 = Gt[k][tf], b1 = Gt[k][tf+1], b2 = Gt[k][tf+2], b3 = Gt[k][tf+3];
            acc[0][0] += a0*b0; acc[0][1] += a0*b1; acc[0][2] += a0*b2; acc[0][3] += a0*b3;
            acc[1][0] += a1*b0; acc[1][1] += a1*b1; acc[1][2] += a1*b2; acc[1][3] += a1*b3;
            acc[2][0] += a2*b0; acc[2][1] += a2*b1; acc[2][2] += a2*b2; acc[2][3] += a2*b3;
            acc[3][0] += a3*b0; acc[3][1] += a3*b1; acc[3][2] += a3*b2; acc[3][3] += a3*b3;
        }
        __syncthreads();
    }
    #pragma unroll
    for (int im = 0; im < 4; im++)
        #pragma unroll
        for (int jf = 0; jf < 4; jf++)
            atomicAdd(&out[(size_t)(m0 + tm + im)*FD + tf + jf], acc[im][jf]);
}

__global__ __launch_bounds__(256) void epilogue_kernel(float* __restrict__ out,
                                                       const float* __restrict__ bm,
                                                       const float* __restrict__ mask) {
    int idx = blockIdx.x * 256 + threadIdx.x;
    if (idx >= 2048*FD) return;
    int node = idx >> 6, f = idx & 63;
    out[idx] = (out[idx] + bm[f]) * mask[node];
}

extern "C" void kernel_launch(void* const* d_in, const int* in_sizes, int n_in,
                              void* d_out, int out_size, void* d_ws, size_t ws_size,
                              hipStream_t stream) {
    const float* x    = (const float*)d_in[0];
    const float* adj  = (const float*)d_in[1];
    const float* mask = (const float*)d_in[2];
    const float* Wl   = (const float*)d_in[3];
    const float* bl   = (const float*)d_in[4];
    const float* Wr   = (const float*)d_in[5];
    const float* br   = (const float*)d_in[6];
    const float* Wm   = (const float*)d_in[9];
    const float* bm   = (const float*)d_in[10];
    float* out = (float*)d_out;
    float* ws  = (float*)d_ws;

    float* tw   = ws + OFF_TW;
    float* wp   = ws + OFF_WP;
    float* sumx = ws + OFF_SUMX;
    float* G1   = ws + OFF_G1;
    float* Gmat = ws + OFF_GMAT;
    float* xl   = ws + OFF_XL;
    float* xr   = ws + OFF_XR;
    float* agg  = ws + OFF_AGG;
    float* Y    = ws + OFF_Y;

    hipLaunchKernelGGL(prep_kernel, dim3(1), dim3(512), 0, stream, tw, wp, sumx);
    hipLaunchKernelGGL(sumx_kernel, dim3(32), dim3(64), 0, stream, x, sumx);
    hipLaunchKernelGGL(proj_kernel, dim3(2048), dim3(64), 0, stream, x, Wl, bl, Wr, br, xl, xr);
    hipLaunchKernelGGL(g1_kernel, dim3(9*QH), dim3(64), 0, stream, Wm, tw, G1);
    hipLaunchKernelGGL(gmat_kernel, dim3(KPAD/2), dim3(64), 0, stream, G1, wp, Gmat);
    hipLaunchKernelGGL(attn_agg_kernel, dim3(2048), dim3(256), 0, stream, x, adj, xl, xr, sumx, agg);
    hipLaunchKernelGGL(fft_y_kernel, dim3(2048), dim3(256), 0, stream, agg, tw, wp, Y);
    hipLaunchKernelGGL(out_init_kernel, dim3(512), dim3(256), 0, stream, out);
    hipLaunchKernelGGL(gemm_kernel, dim3(32, KSPLIT), dim3(256), 0, stream, Y, Gmat, out);
    hipLaunchKernelGGL(epilogue_kernel, dim3(512), dim3(256), 0, stream, out, bm, mask);
}